// Round 3
// baseline (208.364 us; speedup 1.0000x reference)
//
#include <hip/hip_runtime.h>

#define N_ 32
#define C_ 256
#define G_ 16
#define HW_ 3136          // 56*56
#define HW4_ 784          // HW/4
#define EPS_ 1e-12f

// Integer inputs may arrive as int32 or int64; group_sizes[1]==24 in int32
// layout, ==0 (high word of gs[0]) in int64 LE layout. Values < 2^31 so the
// low word is the value in int64 mode. (Observed behavior says int32, but
// keep the detection — it is free and exact.)
__device__ __forceinline__ int rd_int(const int* __restrict__ p, int i, bool is64) {
    return is64 ? p[2 * i] : p[i];
}

// group of permuted position j: g = #{k : prefix[k+1] <= j}
__device__ __forceinline__ int group_of(const int* __restrict__ gs, int j, bool is64) {
    int g = 0, P = 0;
    #pragma unroll
    for (int k = 0; k < G_; k++) {
        P += rd_int(gs, k, is64);
        if (j >= P) g++;
    }
    return g;
}

// ---------------------------------------------------------------------------
// Kernel 1: per permuted row (n, j): sum & sumsq of x[indexes[n*C+j]] row,
// atomically accumulated into per-(n,g) slots in workspace.
// ---------------------------------------------------------------------------
__global__ __launch_bounds__(256) void vgn_reduce(
    const float* __restrict__ x,
    const int*   __restrict__ indexes,
    const int*   __restrict__ group_sizes,
    float*       __restrict__ gsums)        // [N_*G_*2] zero-initialized
{
    const bool is64 = (group_sizes[1] == 0);

    const int row = blockIdx.x;             // n*C + j
    const int n   = row >> 8;
    const int j   = row & 255;
    const int src = rd_int(indexes, row, is64);   // flat source row

    const float4* x4 = (const float4*)(x + (size_t)src * HW_);

    float s = 0.f, s2 = 0.f;
    for (int i = threadIdx.x; i < HW4_; i += 256) {
        float4 v = x4[i];
        s  += v.x + v.y + v.z + v.w;
        s2 += v.x * v.x + v.y * v.y + v.z * v.z + v.w * v.w;
    }

    #pragma unroll
    for (int off = 32; off > 0; off >>= 1) {
        s  += __shfl_down(s,  off);
        s2 += __shfl_down(s2, off);
    }

    __shared__ float ls[4], ls2[4];
    const int wave = threadIdx.x >> 6;
    if ((threadIdx.x & 63) == 0) { ls[wave] = s; ls2[wave] = s2; }
    __syncthreads();

    if (threadIdx.x == 0) {
        float S  = ls[0]  + ls[1]  + ls[2]  + ls[3];
        float S2 = ls2[0] + ls2[1] + ls2[2] + ls2[3];
        const int g = group_of(group_sizes, j, is64);
        atomicAdd(&gsums[(n * G_ + g) * 2 + 0], S);
        atomicAdd(&gsums[(n * G_ + g) * 2 + 1], S2);
    }
}

// ---------------------------------------------------------------------------
// Kernel 2: per permuted row (n, j): normalize with group stats, scale by
// weight[j], shift by bias[j], write back to the SAME flat row (the reverse
// permutation scatter is the inverse of the gather).
// ---------------------------------------------------------------------------
__global__ __launch_bounds__(256) void vgn_norm(
    const float* __restrict__ x,
    const int*   __restrict__ indexes,
    const int*   __restrict__ group_sizes,
    const float* __restrict__ weight,
    const float* __restrict__ bias,
    const float* __restrict__ gsums,
    float*       __restrict__ out)
{
    const bool is64 = (group_sizes[1] == 0);

    const int row = blockIdx.x;             // n*C + j
    const int n   = row >> 8;
    const int j   = row & 255;
    const int src = rd_int(indexes, row, is64);

    const int g   = group_of(group_sizes, j, is64);
    const int gsz = rd_int(group_sizes, g, is64);
    const float cnt = (float)(gsz * HW_);

    const float S   = gsums[(n * G_ + g) * 2 + 0];
    const float S2  = gsums[(n * G_ + g) * 2 + 1];
    const float mu  = S / cnt;
    const float var = (S2 - mu * S) / (cnt - 1.0f);
    const float ivr = rsqrtf(var + EPS_);

    const float scale = ivr * weight[j];
    const float shift = bias[j] - mu * scale;

    const float4* x4 = (const float4*)(x   + (size_t)src * HW_);
    float4*       o4 = (float4*)      (out + (size_t)src * HW_);

    for (int i = threadIdx.x; i < HW4_; i += 256) {
        float4 v = x4[i];
        float4 r;
        r.x = v.x * scale + shift;
        r.y = v.y * scale + shift;
        r.z = v.z * scale + shift;
        r.w = v.w * scale + shift;
        o4[i] = r;
    }
}

// ---------------------------------------------------------------------------
extern "C" void kernel_launch(void* const* d_in, const int* in_sizes, int n_in,
                              void* d_out, int out_size, void* d_ws, size_t ws_size,
                              hipStream_t stream) {
    const float* x           = (const float*)d_in[0];
    const float* weight      = (const float*)d_in[1];
    const float* bias        = (const float*)d_in[2];
    const int*   group_sizes = (const int*)  d_in[3];
    const int*   indexes     = (const int*)  d_in[4];
    // d_in[5] = reverse_indexes (unused: scatter target == gather source)

    float* gsums = (float*)d_ws;            // N_*G_*2 floats = 4 KB

    hipMemsetAsync(gsums, 0, N_ * G_ * 2 * sizeof(float), stream);

    dim3 grid(N_ * C_), block(256);
    vgn_reduce<<<grid, block, 0, stream>>>(x, indexes, group_sizes, gsums);
    vgn_norm  <<<grid, block, 0, stream>>>(x, indexes, group_sizes,
                                           weight, bias, gsums, (float*)d_out);
}

// Round 5
// 200.771 us; speedup vs baseline: 1.0378x; 1.0378x over previous
//
#include <hip/hip_runtime.h>

#define N_ 32
#define C_ 256
#define G_ 16
#define HW_ 3136          // 56*56
#define HW4_ 784          // HW/4
#define EPS_ 1e-12f

typedef float vf4 __attribute__((ext_vector_type(4)));  // clang-native float4
                                                        // (accepted by
                                                        // __builtin_nontemporal_*)

// Integer inputs may arrive as int32 or int64; group_sizes[1]==24 in int32
// layout, ==0 (high word of gs[0]) in int64 LE layout. Values < 2^31 so the
// low word is the value in int64 mode.
__device__ __forceinline__ int rd_int(const int* __restrict__ p, int i, bool is64) {
    return is64 ? p[2 * i] : p[i];
}

// ---------------------------------------------------------------------------
// Kernel 1: per permuted row (n, j): S = sum, S2 = sumsq of x[indexes[row]]
// row, written as plain stores to ws[row*2 + {0,1}]. No zero-init, no atomics.
// ---------------------------------------------------------------------------
__global__ __launch_bounds__(256) void vgn_reduce(
    const float* __restrict__ x,
    const int*   __restrict__ indexes,
    const int*   __restrict__ group_sizes,   // only for is64 detection parity
    float*       __restrict__ rsums)         // [N_*C_*2]
{
    const bool is64 = (group_sizes[1] == 0);

    const int row = blockIdx.x;              // n*C + j
    const int src = rd_int(indexes, row, is64);

    const vf4* x4 = (const vf4*)(x + (size_t)src * HW_);

    float s = 0.f, s2 = 0.f;
    for (int i = threadIdx.x; i < HW4_; i += 256) {
        vf4 v = x4[i];
        s  += v.x + v.y + v.z + v.w;
        s2 += v.x * v.x + v.y * v.y + v.z * v.z + v.w * v.w;
    }

    #pragma unroll
    for (int off = 32; off > 0; off >>= 1) {
        s  += __shfl_down(s,  off);
        s2 += __shfl_down(s2, off);
    }

    __shared__ float ls[4], ls2[4];
    const int wave = threadIdx.x >> 6;
    if ((threadIdx.x & 63) == 0) { ls[wave] = s; ls2[wave] = s2; }
    __syncthreads();

    if (threadIdx.x == 0) {
        rsums[row * 2 + 0] = ls[0]  + ls[1]  + ls[2]  + ls[3];
        rsums[row * 2 + 1] = ls2[0] + ls2[1] + ls2[2] + ls2[3];
    }
}

// ---------------------------------------------------------------------------
// Kernel 2: per permuted row (n, j): combine the contiguous per-row partials
// of j's group (positions [P_g, P_g+gsz), gsz <= 32) into group stats, then
// normalize + affine, writing back to the SAME flat row (reverse permutation
// is the inverse of the gather). Nontemporal stores: out is never re-read.
// ---------------------------------------------------------------------------
__global__ __launch_bounds__(256) void vgn_norm(
    const float* __restrict__ x,
    const int*   __restrict__ indexes,
    const int*   __restrict__ group_sizes,
    const float* __restrict__ weight,
    const float* __restrict__ bias,
    const float* __restrict__ rsums,
    float*       __restrict__ out)
{
    const bool is64 = (group_sizes[1] == 0);

    const int row = blockIdx.x;              // n*C + j
    const int n   = row >> 8;
    const int j   = row & 255;
    const int src = rd_int(indexes, row, is64);

    // group of j via monotone prefix scan; also capture group start P_g
    int g = 0, P = 0, Pg = 0;
    #pragma unroll
    for (int k = 0; k < G_; k++) {
        P += rd_int(group_sizes, k, is64);
        if (j >= P) { g++; Pg = P; }
    }
    const int gsz = rd_int(group_sizes, g, is64);

    // wave 0 sums the gsz (<=32) contiguous per-row partial pairs
    __shared__ float sS, sS2;
    if (threadIdx.x < 64) {
        float a = 0.f, b = 0.f;
        if (threadIdx.x < gsz) {
            const int pr = (n * C_ + Pg + threadIdx.x) * 2;
            a = rsums[pr + 0];
            b = rsums[pr + 1];
        }
        #pragma unroll
        for (int off = 32; off > 0; off >>= 1) {
            a += __shfl_down(a, off);
            b += __shfl_down(b, off);
        }
        if (threadIdx.x == 0) { sS = a; sS2 = b; }
    }
    __syncthreads();

    const float cnt = (float)(gsz * HW_);
    const float S   = sS;
    const float S2  = sS2;
    const float mu  = S / cnt;
    const float var = (S2 - mu * S) / (cnt - 1.0f);
    const float ivr = rsqrtf(var + EPS_);

    const float scale = ivr * weight[j];
    const float shift = bias[j] - mu * scale;

    const vf4* x4 = (const vf4*)(x   + (size_t)src * HW_);
    vf4*       o4 = (vf4*)      (out + (size_t)src * HW_);

    for (int i = threadIdx.x; i < HW4_; i += 256) {
        vf4 v = x4[i];
        vf4 r;
        r.x = v.x * scale + shift;
        r.y = v.y * scale + shift;
        r.z = v.z * scale + shift;
        r.w = v.w * scale + shift;
        __builtin_nontemporal_store(r, &o4[i]);
    }
}

// ---------------------------------------------------------------------------
extern "C" void kernel_launch(void* const* d_in, const int* in_sizes, int n_in,
                              void* d_out, int out_size, void* d_ws, size_t ws_size,
                              hipStream_t stream) {
    const float* x           = (const float*)d_in[0];
    const float* weight      = (const float*)d_in[1];
    const float* bias        = (const float*)d_in[2];
    const int*   group_sizes = (const int*)  d_in[3];
    const int*   indexes     = (const int*)  d_in[4];
    // d_in[5] = reverse_indexes (unused: scatter target == gather source)

    float* rsums = (float*)d_ws;             // N_*C_*2 floats = 64 KB, fully
                                             // written by vgn_reduce (no init)

    dim3 grid(N_ * C_), block(256);
    vgn_reduce<<<grid, block, 0, stream>>>(x, indexes, group_sizes, rsums);
    vgn_norm  <<<grid, block, 0, stream>>>(x, indexes, group_sizes,
                                           weight, bias, rsums, (float*)d_out);
}